// Round 6
// baseline (1574.572 us; speedup 1.0000x reference)
//
#include <hip/hip_runtime.h>
#include <hip/hip_fp16.h>

typedef _Float16 half8  __attribute__((ext_vector_type(8)));
typedef _Float16 half2v __attribute__((ext_vector_type(2)));
typedef float    f32x4  __attribute__((ext_vector_type(4)));

#define MFMA16(af, bf, cf) __builtin_amdgcn_mfma_f32_16x16x32_f16((af), (bf), (cf), 0, 0, 0)

// ---------------- workspace layout (halves) ----------------
#define WS_WL1   0                        // [k1;rk1] packed [nt0..31][kt0..7][512] = 131072
#define WS_RK0   131072                   // rk0 packed [nt][kt0..3][512] = 65536
#define WS_W0    (131072 + 65536)         // W0' = W_in@k0 packed [nt][kt0..2][512] = 49152
#define WS_WOUTT (WS_W0 + 49152)          // Wout^T packed [m0..1][kt0..3][512] = 4096
#define WS_B0    (WS_WOUTT + 4096)        // float b0'[512]  (1024 halves)
#define WS_CB    (WS_B0 + 1024)           // float cb[512] = bout@W0a  (1024 halves)

// ---------------- LDS layout (halves) ----------------
#define PA0 72                             // 64 x-cols + 8 pad
#define PH  136                            // 128 cols + 8 pad
#define PRES 40                            // 32 res-cols + 8 pad
#define L_A0X  0                           // 2 x [16][72] = 2304
#define L_H0   2304                        // 2 x [16][136] = 4352
#define L_H1   (L_H0 + 4352)               // 6656
#define L_RES  (L_H1 + 4352)               // 11008: 8 waves x [16][40] = 5120
#define L_WOUTT (L_RES + 5120)             // 16128: [2m][4kt][512] = 4096
#define L_K1   (L_WOUTT + 4096)            // 20224: k1 kt0..2 [nt][3kt][512] = 49152
#define L_TOT  (L_K1 + 49152)              // 69376 halves = 138752 B

__device__ __forceinline__ float sigm(float x) {
    return __builtin_amdgcn_rcpf(1.0f + __builtin_amdgcn_exp2f(-1.442695041f * x));
}
__device__ __forceinline__ float tanh_(float x) {
    return 1.0f - 2.0f * __builtin_amdgcn_rcpf(__builtin_amdgcn_exp2f(2.885390082f * x) + 1.0f);
}
__device__ __forceinline__ void bar() {
    asm volatile("s_waitcnt lgkmcnt(0)" ::: "memory");
    __builtin_amdgcn_s_barrier();
    asm volatile("" ::: "memory");
}

// ---- pack kernels ----
__global__ void pack_layer_k(const float* __restrict__ kk, const float* __restrict__ rk,
                             _Float16* __restrict__ dst)
{
    int idx  = blockIdx.x * 256 + threadIdx.x;
    int j    = idx & 7;
    int lane = (idx >> 3) & 63;
    int fk   = idx >> 9;
    int kt   = fk & 7;
    int nt   = fk >> 3;
    int w = nt >> 3, ln = nt & 7, g = ln >> 1, hh = ln & 1;
    int col = g*128 + w*32 + hh*16 + (lane & 15);
    int row = kt*32 + (lane >> 4)*8 + j;
    float v = (row < 128) ? kk[row*512 + col] : rk[(row - 128)*512 + col];
    dst[idx] = (_Float16)v;
}

__global__ void pack_rk(const float* __restrict__ rk, _Float16* __restrict__ dst)
{
    int idx = blockIdx.x * 256 + threadIdx.x;
    int j = idx & 7, lane = (idx >> 3) & 63, fk = idx >> 9;
    int kt = fk & 3, nt = fk >> 2;
    int w = nt >> 3, ln = nt & 7, g = ln >> 1, hh = ln & 1;
    int col = g*128 + w*32 + hh*16 + (lane & 15);
    int row = kt*32 + (lane >> 4)*8 + j;
    dst[idx] = (_Float16)rk[row*512 + col];
}

__global__ void pack_w0(const float* __restrict__ W_in, const float* __restrict__ k0,
                        _Float16* __restrict__ dst)
{
    int idx = blockIdx.x * 256 + threadIdx.x;
    int j = idx & 7, lane = (idx >> 3) & 63, fk = idx >> 9;
    int kt = fk % 3, nt = fk / 3;
    int w = nt >> 3, ln = nt & 7, g = ln >> 1, hh = ln & 1;
    int col = g*128 + w*32 + hh*16 + (lane & 15);
    int row = kt*32 + (lane >> 4)*8 + j;   // < 96: rows 0..63 = x, 64..95 = acc
    float s = 0.f;
    #pragma unroll 4
    for (int k = 0; k < 128; ++k) s += W_in[row*128 + k] * k0[k*512 + col];
    dst[idx] = (_Float16)s;
}

__global__ void pack_b0(const float* __restrict__ b_in, const float* __restrict__ k0,
                        const float* __restrict__ bb0, float* __restrict__ b0p)
{
    int col = blockIdx.x * 256 + threadIdx.x;
    float s = bb0[col];
    #pragma unroll 4
    for (int k = 0; k < 128; ++k) s += b_in[k] * k0[k*512 + col];
    b0p[col] = s;
}

// Wout^T as A-frags: dst[(m*4+kt)*512 + lane*8 + j] = Wout[kt*32+lg*8+j][m*16+l15]
__global__ void pack_woutT(const float* __restrict__ W_out, _Float16* __restrict__ dst)
{
    int idx = blockIdx.x * 256 + threadIdx.x;   // < 4096
    int j = idx & 7, lane = (idx >> 3) & 63, fk = idx >> 9;
    int kt = fk & 3, m = fk >> 2;
    int row = kt*32 + (lane >> 4)*8 + j;        // h-index (K)
    int col = m*16 + (lane & 15);               // res-col
    dst[idx] = (_Float16)W_out[row*32 + col];
}

// cb[zcol] = sum_c bout[c] * W0a[c][zcol],  W0a = W_in rows 64..95 @ k0
__global__ void pack_cb(const float* __restrict__ W_in, const float* __restrict__ k0,
                        const float* __restrict__ bout, float* __restrict__ cbp)
{
    int zc = blockIdx.x * 256 + threadIdx.x;    // < 512
    float s = 0.f;
    for (int c = 0; c < 32; ++c) {
        float wv = 0.f;
        #pragma unroll 4
        for (int k = 0; k < 128; ++k) wv += W_in[(64 + c)*128 + k] * k0[k*512 + zc];
        s += bout[c] * wv;
    }
    cbp[zc] = s;
}

// 8 waves (2/SIMD). Wave W=(w4,hh) owns hidden cols w4*32+hh*16+[0,16).
// Recurrence: za (f32, regs) carries acc@W0a; res fed back via wave-local
// transpose dance; 2 barriers/step; out-stores fire-and-forget.
__global__ __launch_bounds__(512, 2)
void acclstm_main(const float* __restrict__ xin,
                  const _Float16* __restrict__ wl1p, const _Float16* __restrict__ rk0p,
                  const _Float16* __restrict__ w0p,  const _Float16* __restrict__ woutTp,
                  const float* __restrict__ b0p, const float* __restrict__ cbp,
                  const float* __restrict__ bb1, const float* __restrict__ bout,
                  float* __restrict__ out)
{
    __shared__ __align__(16) _Float16 lds[L_TOT];
    const int tid  = threadIdx.x;
    const int W    = tid >> 6;
    const int lane = tid & 63;
    const int w4   = W & 3;
    const int hh   = W >> 2;
    const int l15  = lane & 15;
    const int lg   = lane >> 4;
    const int b0   = blockIdx.x << 4;
    const int colw = w4*32 + hh*16 + l15;
    const int nt0 = w4*8 + 0 + hh, nt1 = w4*8 + 2 + hh, nt2 = w4*8 + 4 + hh, nt3 = w4*8 + 6 + hh;

    // ---- LDS fills ----
    for (int i = tid; i < 6144; i += 512) {       // k1 kt0..2
        int h = i << 3, nt = h / 1536, rem = h % 1536;
        *reinterpret_cast<uint4*>(&lds[L_K1 + h]) =
            *reinterpret_cast<const uint4*>(&wl1p[nt*4096 + rem]);
    }
    *reinterpret_cast<uint4*>(&lds[L_WOUTT + (tid << 3)]) =
        *reinterpret_cast<const uint4*>(&woutTp[tid << 3]);
    {   // zero H0[0] and H1[0] COMPLETELY (272 uint4 = 2176 halves each).
        // R5 bug: `else if (tid < 544)` left 256 halves of H1[0] uninitialized
        // (tid max 511) -> garbage h1(-1) poisoned za at t=0 -> NaN.
        uint4 z; z.x = z.y = z.z = z.w = 0u;
        if (tid < 272) {
            *reinterpret_cast<uint4*>(&lds[L_H0 + (tid << 3)]) = z;
            *reinterpret_cast<uint4*>(&lds[L_H1 + (tid << 3)]) = z;
        }
    }

    // ---- persistent weight fragments ----
    half8 rk0r[4][4], rk1r[4][4], k1r[4], w0a[4];
    {
        const int nts[4] = {nt0, nt1, nt2, nt3};
        #pragma unroll
        for (int g = 0; g < 4; ++g) {
            const int nt = nts[g];
            #pragma unroll
            for (int kt = 0; kt < 4; ++kt)
                rk0r[g][kt] = *reinterpret_cast<const half8*>(&rk0p[(nt*4 + kt)*512 + lane*8]);
            #pragma unroll
            for (int kt = 0; kt < 4; ++kt)
                rk1r[g][kt] = *reinterpret_cast<const half8*>(&wl1p[(nt*8 + 4 + kt)*512 + lane*8]);
            k1r[g] = *reinterpret_cast<const half8*>(&wl1p[(nt*8 + 3)*512 + lane*8]);
            w0a[g] = *reinterpret_cast<const half8*>(&w0p[(nt*3 + 2)*512 + lane*8]);
        }
    }
    float b1v[4], cbv[4];
    f32x4 za[4];
    #pragma unroll
    for (int g = 0; g < 4; ++g) {
        b1v[g] = bb1[g*128 + colw];
        cbv[g] = cbp[g*128 + colw];
        float z0i = b0p[g*128 + colw] - cbv[g];   // dance at t=0 adds cb back
        za[g] = (f32x4){z0i, z0i, z0i, z0i};
    }
    float boutv4[4];
    #pragma unroll
    for (int r = 0; r < 4; ++r)
        boutv4[r] = bout[(W < 2 ? W : 0)*16 + lg*4 + r];

    f32x4 c0 = {0.f,0.f,0.f,0.f}, c1 = {0.f,0.f,0.f,0.f};

    const int xrow = tid >> 5, xc2 = (tid & 31) << 1;
    const int resw = L_RES + W*640 + l15*PRES;    // wave-private transpose buffer

    __syncthreads();
    float2 xr = *reinterpret_cast<const float2*>(&xin[(size_t)(b0 + xrow)*16384 + xc2]);
    {
        half2v xh = { (_Float16)xr.x, (_Float16)xr.y };
        *reinterpret_cast<half2v*>(&lds[L_A0X + xrow*PA0 + xc2]) = xh;
    }
    xr = *reinterpret_cast<const float2*>(&xin[(size_t)(b0 + xrow)*16384 + 64 + xc2]);
    __syncthreads();

    auto step = [&](auto PARc, int t) {
        constexpr int PAR = decltype(PARc)::value;
        constexpr int A0r = L_A0X + PAR*1152, A0w = L_A0X + (PAR^1)*1152;
        constexpr int H0r = L_H0 + PAR*2176,  H0w = L_H0 + (PAR^1)*2176;
        constexpr int H1r = L_H1 + PAR*2176,  H1w = L_H1 + (PAR^1)*2176;

        // ======== dance: res(t-1) = h1(t-1)@Wout; za += resA@W0a + cb ========
        {
            f32x4 rr0 = {0.f,0.f,0.f,0.f}, rr1 = {0.f,0.f,0.f,0.f};
            #pragma unroll
            for (int kt = 0; kt < 4; ++kt) {
                half8 hf  = *reinterpret_cast<const half8*>(&lds[H1r + l15*PH + kt*32 + lg*8]);
                half8 wt0 = *reinterpret_cast<const half8*>(&lds[L_WOUTT + (0*4 + kt)*512 + lane*8]);
                half8 wt1 = *reinterpret_cast<const half8*>(&lds[L_WOUTT + (1*4 + kt)*512 + lane*8]);
                rr0 = MFMA16(wt0, hf, rr0);      // D: [c = lg*4+r][b = l15]
                rr1 = MFMA16(wt1, hf, rr1);
            }
            // transpose to A-frag layout via wave-private LDS
            #pragma unroll
            for (int r = 0; r < 4; ++r) {
                lds[resw + lg*4 + r]      = (_Float16)rr0[r];
                lds[resw + 16 + lg*4 + r] = (_Float16)rr1[r];
            }
            asm volatile("s_waitcnt lgkmcnt(0)" ::: "memory");
            half8 resA = *reinterpret_cast<const half8*>(&lds[resw + lg*8]);
            #pragma unroll
            for (int g = 0; g < 4; ++g) {
                za[g] = MFMA16(resA, w0a[g], za[g]);
                #pragma unroll
                for (int r = 0; r < 4; ++r) za[g][r] += cbv[g];
            }
            if (t && W < 2) {
                const f32x4& rrs = (W == 0) ? rr0 : rr1;
                #pragma unroll
                for (int r = 0; r < 4; ++r)
                    out[(size_t)(b0 + l15)*8192 + (t-1)*32 + W*16 + lg*4 + r] = rrs[r] + boutv4[r];
            }
        }

        // ======== seg1: z0 = za + x@W0x + h0_prev@rk0 -> h0 ========
        {
            half8 ax0 = *reinterpret_cast<const half8*>(&lds[A0r + l15*PA0 +  0 + lg*8]);
            half8 ax1 = *reinterpret_cast<const half8*>(&lds[A0r + l15*PA0 + 32 + lg*8]);
            half8 wx00 = *reinterpret_cast<const half8*>(&w0p[(nt0*3 + 0)*512 + lane*8]);
            half8 wx01 = *reinterpret_cast<const half8*>(&w0p[(nt0*3 + 1)*512 + lane*8]);
            half8 wx10 = *reinterpret_cast<const half8*>(&w0p[(nt1*3 + 0)*512 + lane*8]);
            half8 wx11 = *reinterpret_cast<const half8*>(&w0p[(nt1*3 + 1)*512 + lane*8]);
            half8 wx20 = *reinterpret_cast<const half8*>(&w0p[(nt2*3 + 0)*512 + lane*8]);
            half8 wx21 = *reinterpret_cast<const half8*>(&w0p[(nt2*3 + 1)*512 + lane*8]);
            half8 wx30 = *reinterpret_cast<const half8*>(&w0p[(nt3*3 + 0)*512 + lane*8]);
            half8 wx31 = *reinterpret_cast<const half8*>(&w0p[(nt3*3 + 1)*512 + lane*8]);
            f32x4 z0 = MFMA16(ax0, wx00, za[0]); z0 = MFMA16(ax1, wx01, z0);
            f32x4 z1 = MFMA16(ax0, wx10, za[1]); z1 = MFMA16(ax1, wx11, z1);
            f32x4 z2 = MFMA16(ax0, wx20, za[2]); z2 = MFMA16(ax1, wx21, z2);
            f32x4 z3 = MFMA16(ax0, wx30, za[3]); z3 = MFMA16(ax1, wx31, z3);
            #pragma unroll
            for (int kt = 0; kt < 4; ++kt) {
                half8 hf = *reinterpret_cast<const half8*>(&lds[H0r + l15*PH + kt*32 + lg*8]);
                z0 = MFMA16(hf, rk0r[0][kt], z0);
                z1 = MFMA16(hf, rk0r[1][kt], z1);
                z2 = MFMA16(hf, rk0r[2][kt], z2);
                z3 = MFMA16(hf, rk0r[3][kt], z3);
            }
            #pragma unroll
            for (int r = 0; r < 4; ++r) {
                float iv = sigm (z0[r]);
                float fv = sigm (z1[r]);
                float gv = tanh_(z2[r]);
                float ov = sigm (z3[r]);
                float cn = fv * c0[r] + iv * gv;
                c0[r] = cn;
                lds[H0w + (lg*4 + r)*PH + colw] = (_Float16)(ov * tanh_(cn));
            }
        }
        // stage x(t+1); prefetch x(t+2)
        {
            half2v xh = { (_Float16)xr.x, (_Float16)xr.y };
            *reinterpret_cast<half2v*>(&lds[A0w + xrow*PA0 + xc2]) = xh;
            int tn = t + 2; if (tn > 255) tn = 255;
            xr = *reinterpret_cast<const float2*>(&xin[(size_t)(b0 + xrow)*16384 + tn*64 + xc2]);
        }
        bar();  // barA: h0(t) + x(t+1) ready

        // ======== seg2: z1 = h0@k1 + h1_prev@rk1 -> h1 ========
        {
            f32x4 z0 = {b1v[0],b1v[0],b1v[0],b1v[0]};
            f32x4 z1 = {b1v[1],b1v[1],b1v[1],b1v[1]};
            f32x4 z2 = {b1v[2],b1v[2],b1v[2],b1v[2]};
            f32x4 z3 = {b1v[3],b1v[3],b1v[3],b1v[3]};
            #pragma unroll
            for (int kt = 0; kt < 3; ++kt) {
                half8 hf = *reinterpret_cast<const half8*>(&lds[H0w + l15*PH + kt*32 + lg*8]);
                z0 = MFMA16(hf, *reinterpret_cast<const half8*>(&lds[L_K1 + (nt0*3 + kt)*512 + lane*8]), z0);
                z1 = MFMA16(hf, *reinterpret_cast<const half8*>(&lds[L_K1 + (nt1*3 + kt)*512 + lane*8]), z1);
                z2 = MFMA16(hf, *reinterpret_cast<const half8*>(&lds[L_K1 + (nt2*3 + kt)*512 + lane*8]), z2);
                z3 = MFMA16(hf, *reinterpret_cast<const half8*>(&lds[L_K1 + (nt3*3 + kt)*512 + lane*8]), z3);
            }
            {
                half8 hf = *reinterpret_cast<const half8*>(&lds[H0w + l15*PH + 3*32 + lg*8]);
                z0 = MFMA16(hf, k1r[0], z0);
                z1 = MFMA16(hf, k1r[1], z1);
                z2 = MFMA16(hf, k1r[2], z2);
                z3 = MFMA16(hf, k1r[3], z3);
            }
            #pragma unroll
            for (int kt = 0; kt < 4; ++kt) {
                half8 hf = *reinterpret_cast<const half8*>(&lds[H1r + l15*PH + kt*32 + lg*8]);
                z0 = MFMA16(hf, rk1r[0][kt], z0);
                z1 = MFMA16(hf, rk1r[1][kt], z1);
                z2 = MFMA16(hf, rk1r[2][kt], z2);
                z3 = MFMA16(hf, rk1r[3][kt], z3);
            }
            #pragma unroll
            for (int r = 0; r < 4; ++r) {
                float iv = sigm (z0[r]);
                float fv = sigm (z1[r]);
                float gv = tanh_(z2[r]);
                float ov = sigm (z3[r]);
                float cn = fv * c1[r] + iv * gv;
                c1[r] = cn;
                lds[H1w + (lg*4 + r)*PH + colw] = (_Float16)(ov * tanh_(cn));
            }
        }
        bar();  // barB: h1(t) ready
    };

    #pragma unroll 1
    for (int t = 0; t < 256; t += 2) {
        step(std::integral_constant<int,0>{}, t);
        step(std::integral_constant<int,1>{}, t + 1);
    }

    // epilogue: out(255) from h1(255) in H1[0]
    {
        f32x4 rr0 = {0.f,0.f,0.f,0.f}, rr1 = {0.f,0.f,0.f,0.f};
        #pragma unroll
        for (int kt = 0; kt < 4; ++kt) {
            half8 hf  = *reinterpret_cast<const half8*>(&lds[L_H1 + l15*PH + kt*32 + lg*8]);
            half8 wt0 = *reinterpret_cast<const half8*>(&lds[L_WOUTT + (0*4 + kt)*512 + lane*8]);
            half8 wt1 = *reinterpret_cast<const half8*>(&lds[L_WOUTT + (1*4 + kt)*512 + lane*8]);
            rr0 = MFMA16(wt0, hf, rr0);
            rr1 = MFMA16(wt1, hf, rr1);
        }
        if (W < 2) {
            const f32x4& rrs = (W == 0) ? rr0 : rr1;
            #pragma unroll
            for (int r = 0; r < 4; ++r)
                out[(size_t)(b0 + l15)*8192 + 255*32 + W*16 + lg*4 + r] = rrs[r] + boutv4[r];
        }
    }
}

extern "C" void kernel_launch(void* const* d_in, const int* in_sizes, int n_in,
                              void* d_out, int out_size, void* d_ws, size_t ws_size,
                              hipStream_t stream) {
    (void)in_sizes; (void)n_in; (void)out_size; (void)ws_size;
    const float* x     = (const float*)d_in[0];
    const float* W_in  = (const float*)d_in[1];
    const float* b_in  = (const float*)d_in[2];
    const float* k0    = (const float*)d_in[3];
    const float* rk0   = (const float*)d_in[4];
    const float* bb0   = (const float*)d_in[5];
    const float* k1    = (const float*)d_in[6];
    const float* rk1   = (const float*)d_in[7];
    const float* bb1   = (const float*)d_in[8];
    const float* W_out = (const float*)d_in[9];
    const float* b_out = (const float*)d_in[10];
    float* out = (float*)d_out;

    _Float16* ws     = (_Float16*)d_ws;
    _Float16* wl1p   = ws + WS_WL1;
    _Float16* rk0p   = ws + WS_RK0;
    _Float16* w0p    = ws + WS_W0;
    _Float16* woutTp = ws + WS_WOUTT;
    float*    b0p    = (float*)(ws + WS_B0);
    float*    cbp    = (float*)(ws + WS_CB);

    pack_layer_k<<<512, 256, 0, stream>>>(k1, rk1, wl1p);
    pack_rk     <<<256, 256, 0, stream>>>(rk0, rk0p);
    pack_w0     <<<192, 256, 0, stream>>>(W_in, k0, w0p);
    pack_b0     <<<2,   256, 0, stream>>>(b_in, k0, bb0, b0p);
    pack_woutT  <<<16,  256, 0, stream>>>(W_out, woutTp);
    pack_cb     <<<2,   256, 0, stream>>>(W_in, k0, b_out, cbp);
    acclstm_main<<<256, 512, 0, stream>>>(x, wl1p, rk0p, w0p, woutTp,
                                          b0p, cbp, bb1, b_out, out);
}

// Round 7
// 1248.006 us; speedup vs baseline: 1.2617x; 1.2617x over previous
//
#include <hip/hip_runtime.h>
#include <hip/hip_fp16.h>

typedef _Float16 half8  __attribute__((ext_vector_type(8)));
typedef float    f32x4  __attribute__((ext_vector_type(4)));

#define MFMA16(af, bf, cf) __builtin_amdgcn_mfma_f32_16x16x32_f16((af), (bf), (cf), 0, 0, 0)

// ---------------- workspace layout (halves) ----------------
#define WS_WL1  0                         // [k1;rk1] packed [nt0..31][kt0..7][512] = 131072
#define WS_RK0  131072                    // rk0 packed [nt][kt0..3][512] = 65536
#define WS_W0   (131072 + 65536)          // W0' = W_in@k0 packed [nt][kt0..2][512] = 49152
#define WS_WOUT (WS_W0 + 49152)           // W_out packed [nt0..1][kt0..3][512] = 4096
#define WS_B0   (WS_WOUT + 4096)          // float b0'[512] (1024 halves)

// ---------------- LDS layout (halves) ----------------
#define PACC 40                            // 32 acc cols + 8 pad
#define PH   136                           // 128 cols + 8 pad
#define L_ACC  0                           // 2 x [16][40] = 1280
#define L_H0   1280                        // 2 x [16][136] = 4352
#define L_H1   (L_H0 + 4352)               // 5632
#define L_WOUT (L_H1 + 4352)               // 9984: [2nt][4kt][512] = 4096
#define L_K1   (L_WOUT + 4096)             // 14080: k1 kt0..3 [nt][kt][512] = 65536
#define L_TOT  (L_K1 + 65536)              // 79616 halves = 159232 B

__device__ __forceinline__ float sigm(float x) {
    return __builtin_amdgcn_rcpf(1.0f + __builtin_amdgcn_exp2f(-1.442695041f * x));
}
__device__ __forceinline__ float tanh_(float x) {
    return 1.0f - 2.0f * __builtin_amdgcn_rcpf(__builtin_amdgcn_exp2f(2.885390082f * x) + 1.0f);
}
// raw barrier: drain LDS only; global loads/stores stay in flight.
__device__ __forceinline__ void bar() {
    asm volatile("s_waitcnt lgkmcnt(0)" ::: "memory");
    __builtin_amdgcn_s_barrier();
    asm volatile("" ::: "memory");
}

// ---- pack kernels ----
__global__ void pack_layer_k(const float* __restrict__ kk, const float* __restrict__ rk,
                             _Float16* __restrict__ dst)
{
    int idx  = blockIdx.x * 256 + threadIdx.x;
    int j    = idx & 7;
    int lane = (idx >> 3) & 63;
    int fk   = idx >> 9;
    int kt   = fk & 7;
    int nt   = fk >> 3;
    int w = nt >> 3, ln = nt & 7, g = ln >> 1, hh = ln & 1;
    int col = g*128 + w*32 + hh*16 + (lane & 15);
    int row = kt*32 + (lane >> 4)*8 + j;
    float v = (row < 128) ? kk[row*512 + col] : rk[(row - 128)*512 + col];
    dst[idx] = (_Float16)v;
}

__global__ void pack_rk(const float* __restrict__ rk, _Float16* __restrict__ dst)
{
    int idx = blockIdx.x * 256 + threadIdx.x;
    int j = idx & 7, lane = (idx >> 3) & 63, fk = idx >> 9;
    int kt = fk & 3, nt = fk >> 2;
    int w = nt >> 3, ln = nt & 7, g = ln >> 1, hh = ln & 1;
    int col = g*128 + w*32 + hh*16 + (lane & 15);
    int row = kt*32 + (lane >> 4)*8 + j;
    dst[idx] = (_Float16)rk[row*512 + col];
}

__global__ void pack_w0(const float* __restrict__ W_in, const float* __restrict__ k0,
                        _Float16* __restrict__ dst)
{
    int idx = blockIdx.x * 256 + threadIdx.x;
    int j = idx & 7, lane = (idx >> 3) & 63, fk = idx >> 9;
    int kt = fk % 3, nt = fk / 3;
    int w = nt >> 3, ln = nt & 7, g = ln >> 1, hh = ln & 1;
    int col = g*128 + w*32 + hh*16 + (lane & 15);
    int row = kt*32 + (lane >> 4)*8 + j;   // rows 0..63 = x, 64..95 = acc
    float s = 0.f;
    #pragma unroll 4
    for (int k = 0; k < 128; ++k) s += W_in[row*128 + k] * k0[k*512 + col];
    dst[idx] = (_Float16)s;
}

__global__ void pack_b0(const float* __restrict__ b_in, const float* __restrict__ k0,
                        const float* __restrict__ bb0, float* __restrict__ b0p)
{
    int col = blockIdx.x * 256 + threadIdx.x;
    float s = bb0[col];
    #pragma unroll 4
    for (int k = 0; k < 128; ++k) s += b_in[k] * k0[k*512 + col];
    b0p[col] = s;
}

__global__ void pack_wout(const float* __restrict__ W_out, _Float16* __restrict__ dst)
{
    int idx = blockIdx.x * 256 + threadIdx.x;
    int j = idx & 7, lane = (idx >> 3) & 63, fk = idx >> 9;
    int kt = fk & 3, nt = fk >> 2;
    int col = nt*16 + (lane & 15);
    int row = kt*32 + (lane >> 4)*8 + j;
    dst[idx] = (_Float16)W_out[row*32 + col];
}

// 8 waves (2/SIMD). Wave W=(w4,hh) owns hidden cols w4*32+hh*16+[0,16) of every
// gate for both layers. x_t is loaded straight from global into A-fragment
// registers one step ahead (no LDS staging); only acc round-trips through LDS.
__global__ __launch_bounds__(512, 2)
void acclstm_main(const float* __restrict__ xin,
                  const _Float16* __restrict__ wl1p, const _Float16* __restrict__ rk0p,
                  const _Float16* __restrict__ w0p,  const _Float16* __restrict__ woutp,
                  const float* __restrict__ b0p, const float* __restrict__ bb1,
                  const float* __restrict__ bout, float* __restrict__ out)
{
    __shared__ __align__(16) _Float16 lds[L_TOT];
    const int tid  = threadIdx.x;
    const int W    = tid >> 6;
    const int lane = tid & 63;
    const int w4   = W & 3;
    const int hh   = W >> 2;
    const int l15  = lane & 15;
    const int lg   = lane >> 4;
    const int b0   = blockIdx.x << 4;
    const int colw = w4*32 + hh*16 + l15;

    // ---- LDS fills ----
    for (int i = tid; i < 8192; i += 512) {       // k1 kt0..3
        int h = i << 3, nt = h >> 11, rem = h & 2047;
        *reinterpret_cast<uint4*>(&lds[L_K1 + h]) =
            *reinterpret_cast<const uint4*>(&wl1p[nt*4096 + rem]);
    }
    *reinterpret_cast<uint4*>(&lds[L_WOUT + (tid << 3)]) =
        *reinterpret_cast<const uint4*>(&woutp[tid << 3]);
    {   // zero H0[0], H1[0] (272 uint4 each) and ACC both parities (160 uint4)
        uint4 z; z.x = z.y = z.z = z.w = 0u;
        if (tid < 272) {
            *reinterpret_cast<uint4*>(&lds[L_H0 + (tid << 3)]) = z;
            *reinterpret_cast<uint4*>(&lds[L_H1 + (tid << 3)]) = z;
        }
        if (tid < 160)
            *reinterpret_cast<uint4*>(&lds[L_ACC + (tid << 3)]) = z;
    }

    // ---- persistent weight fragments ----
    half8 w0r[4][2], w0a[4], rk0r[4][4], rk1r[4][4];
    #pragma unroll
    for (int g = 0; g < 4; ++g) {
        const int nt = w4*8 + g*2 + hh;
        w0r[g][0] = *reinterpret_cast<const half8*>(&w0p[(nt*3 + 0)*512 + lane*8]);
        w0r[g][1] = *reinterpret_cast<const half8*>(&w0p[(nt*3 + 1)*512 + lane*8]);
        w0a[g]    = *reinterpret_cast<const half8*>(&w0p[(nt*3 + 2)*512 + lane*8]);
        #pragma unroll
        for (int kt = 0; kt < 4; ++kt)
            rk0r[g][kt] = *reinterpret_cast<const half8*>(&rk0p[(nt*4 + kt)*512 + lane*8]);
        #pragma unroll
        for (int kt = 0; kt < 4; ++kt)
            rk1r[g][kt] = *reinterpret_cast<const half8*>(&wl1p[(nt*8 + 4 + kt)*512 + lane*8]);
    }
    float b0v[4], b1v[4];
    #pragma unroll
    for (int g = 0; g < 4; ++g) {
        b0v[g] = b0p[g*128 + colw];
        b1v[g] = bb1[g*128 + colw];
    }
    const float boutv = (W < 2) ? bout[W*16 + l15] : 0.0f;

    f32x4 c0 = {0.f,0.f,0.f,0.f}, c1 = {0.f,0.f,0.f,0.f}, accv = {0.f,0.f,0.f,0.f};

    // x fragment source: lane (lg,l15) reads x[b0+l15][t*64 + kt*32 + lg*8 + j]
    const float* xrow = xin + (size_t)(b0 + l15)*16384 + lg*8;
    float4 xq0, xq1, xq2, xq3;   // t+1 prefetch (f32), converted mid-seg1
    xq0 = *reinterpret_cast<const float4*>(xrow + 0);
    xq1 = *reinterpret_cast<const float4*>(xrow + 4);
    xq2 = *reinterpret_cast<const float4*>(xrow + 32);
    xq3 = *reinterpret_cast<const float4*>(xrow + 36);

    __syncthreads();

    auto step = [&](auto PARc, int t) {
        constexpr int PAR = decltype(PARc)::value;
        constexpr int ACCr = L_ACC + PAR*640, ACCw = L_ACC + (PAR^1)*640;
        constexpr int H0r = L_H0 + PAR*2176,  H0w = L_H0 + (PAR^1)*2176;
        constexpr int H1r = L_H1 + PAR*2176,  H1w = L_H1 + (PAR^1)*2176;

        // ======== seg1: z0 = b0' + x@W0x + acc@W0a + h0_prev@rk0 -> h0 ========
        {
            half8 aac = *reinterpret_cast<const half8*>(&lds[ACCr + l15*PACC + lg*8]);
            f32x4 z0 = {b0v[0],b0v[0],b0v[0],b0v[0]};
            f32x4 z1 = {b0v[1],b0v[1],b0v[1],b0v[1]};
            f32x4 z2 = {b0v[2],b0v[2],b0v[2],b0v[2]};
            f32x4 z3 = {b0v[3],b0v[3],b0v[3],b0v[3]};
            #pragma unroll
            for (int kt = 0; kt < 4; ++kt) {
                half8 hf = *reinterpret_cast<const half8*>(&lds[H0r + l15*PH + kt*32 + lg*8]);
                z0 = MFMA16(hf, rk0r[0][kt], z0);
                z1 = MFMA16(hf, rk0r[1][kt], z1);
                z2 = MFMA16(hf, rk0r[2][kt], z2);
                z3 = MFMA16(hf, rk0r[3][kt], z3);
            }
            // convert prefetched x (loaded last tail; vmcnt waits land here)
            half8 ax0 = { (_Float16)xq0.x, (_Float16)xq0.y, (_Float16)xq0.z, (_Float16)xq0.w,
                          (_Float16)xq1.x, (_Float16)xq1.y, (_Float16)xq1.z, (_Float16)xq1.w };
            half8 ax1 = { (_Float16)xq2.x, (_Float16)xq2.y, (_Float16)xq2.z, (_Float16)xq2.w,
                          (_Float16)xq3.x, (_Float16)xq3.y, (_Float16)xq3.z, (_Float16)xq3.w };
            z0 = MFMA16(ax0, w0r[0][0], z0); z1 = MFMA16(ax0, w0r[1][0], z1);
            z2 = MFMA16(ax0, w0r[2][0], z2); z3 = MFMA16(ax0, w0r[3][0], z3);
            z0 = MFMA16(ax1, w0r[0][1], z0); z1 = MFMA16(ax1, w0r[1][1], z1);
            z2 = MFMA16(ax1, w0r[2][1], z2); z3 = MFMA16(ax1, w0r[3][1], z3);
            z0 = MFMA16(aac, w0a[0], z0);    z1 = MFMA16(aac, w0a[1], z1);
            z2 = MFMA16(aac, w0a[2], z2);    z3 = MFMA16(aac, w0a[3], z3);
            #pragma unroll
            for (int r = 0; r < 4; ++r) {
                float iv = sigm (z0[r]);
                float fv = sigm (z1[r]);
                float gv = tanh_(z2[r]);
                float ov = sigm (z3[r]);
                float cn = fv * c0[r] + iv * gv;
                c0[r] = cn;
                lds[H0w + (lg*4 + r)*PH + colw] = (_Float16)(ov * tanh_(cn));
            }
        }
        bar();  // barA: h0(t) ready

        // ======== seg2: z1 = h0@k1(LDS) + h1_prev@rk1 -> h1 ========
        {
            f32x4 z0 = {b1v[0],b1v[0],b1v[0],b1v[0]};
            f32x4 z1 = {b1v[1],b1v[1],b1v[1],b1v[1]};
            f32x4 z2 = {b1v[2],b1v[2],b1v[2],b1v[2]};
            f32x4 z3 = {b1v[3],b1v[3],b1v[3],b1v[3]};
            #pragma unroll
            for (int kt = 0; kt < 4; ++kt) {
                half8 hf = *reinterpret_cast<const half8*>(&lds[H0w + l15*PH + kt*32 + lg*8]);
                z0 = MFMA16(hf, *reinterpret_cast<const half8*>(&lds[L_K1 + ((w4*8 + 0 + hh)*4 + kt)*512 + lane*8]), z0);
                z1 = MFMA16(hf, *reinterpret_cast<const half8*>(&lds[L_K1 + ((w4*8 + 2 + hh)*4 + kt)*512 + lane*8]), z1);
                z2 = MFMA16(hf, *reinterpret_cast<const half8*>(&lds[L_K1 + ((w4*8 + 4 + hh)*4 + kt)*512 + lane*8]), z2);
                z3 = MFMA16(hf, *reinterpret_cast<const half8*>(&lds[L_K1 + ((w4*8 + 6 + hh)*4 + kt)*512 + lane*8]), z3);
            }
            #pragma unroll
            for (int kt = 0; kt < 4; ++kt) {
                half8 hf = *reinterpret_cast<const half8*>(&lds[H1r + l15*PH + kt*32 + lg*8]);
                z0 = MFMA16(hf, rk1r[0][kt], z0);
                z1 = MFMA16(hf, rk1r[1][kt], z1);
                z2 = MFMA16(hf, rk1r[2][kt], z2);
                z3 = MFMA16(hf, rk1r[3][kt], z3);
            }
            #pragma unroll
            for (int r = 0; r < 4; ++r) {
                float iv = sigm (z0[r]);
                float fv = sigm (z1[r]);
                float gv = tanh_(z2[r]);
                float ov = sigm (z3[r]);
                float cn = fv * c1[r] + iv * gv;
                c1[r] = cn;
                lds[H1w + (lg*4 + r)*PH + colw] = (_Float16)(ov * tanh_(cn));
            }
        }
        bar();  // barB: h1(t) ready

        // ======== tail: x(t+1) prefetch issue; GEMM4; acc stage ========
        {
            const int tn = (t < 255) ? (t + 1) : t;
            const float* xb = xrow + tn*64;
            xq0 = *reinterpret_cast<const float4*>(xb + 0);
            xq1 = *reinterpret_cast<const float4*>(xb + 4);
            xq2 = *reinterpret_cast<const float4*>(xb + 32);
            xq3 = *reinterpret_cast<const float4*>(xb + 36);
        }
        if (W < 2) {
            f32x4 rr = {boutv,boutv,boutv,boutv};
            #pragma unroll
            for (int kt = 0; kt < 4; ++kt) {
                half8 af = *reinterpret_cast<const half8*>(&lds[H1w + l15*PH + kt*32 + lg*8]);
                half8 wf = *reinterpret_cast<const half8*>(&lds[L_WOUT + (W*4 + kt)*512 + lane*8]);
                rr = MFMA16(af, wf, rr);
            }
            #pragma unroll
            for (int r = 0; r < 4; ++r) {
                float res = rr[r];
                out[(size_t)(b0 + lg*4 + r)*8192 + t*32 + W*16 + l15] = res;
                accv[r] += res;
                lds[ACCw + (lg*4 + r)*PACC + W*16 + l15] = (_Float16)accv[r];
            }
        }
        bar();  // barC: acc(t) staged for seg1(t+1)
    };

    #pragma unroll 1
    for (int t = 0; t < 256; t += 2) {
        step(std::integral_constant<int,0>{}, t);
        step(std::integral_constant<int,1>{}, t + 1);
    }
}

extern "C" void kernel_launch(void* const* d_in, const int* in_sizes, int n_in,
                              void* d_out, int out_size, void* d_ws, size_t ws_size,
                              hipStream_t stream) {
    (void)in_sizes; (void)n_in; (void)out_size; (void)ws_size;
    const float* x     = (const float*)d_in[0];
    const float* W_in  = (const float*)d_in[1];
    const float* b_in  = (const float*)d_in[2];
    const float* k0    = (const float*)d_in[3];
    const float* rk0   = (const float*)d_in[4];
    const float* bb0   = (const float*)d_in[5];
    const float* k1    = (const float*)d_in[6];
    const float* rk1   = (const float*)d_in[7];
    const float* bb1   = (const float*)d_in[8];
    const float* W_out = (const float*)d_in[9];
    const float* b_out = (const float*)d_in[10];
    float* out = (float*)d_out;

    _Float16* ws    = (_Float16*)d_ws;
    _Float16* wl1p  = ws + WS_WL1;
    _Float16* rk0p  = ws + WS_RK0;
    _Float16* w0p   = ws + WS_W0;
    _Float16* woutp = ws + WS_WOUT;
    float*    b0p   = (float*)(ws + WS_B0);

    pack_layer_k<<<512, 256, 0, stream>>>(k1, rk1, wl1p);
    pack_rk     <<<256, 256, 0, stream>>>(rk0, rk0p);
    pack_w0     <<<192, 256, 0, stream>>>(W_in, k0, w0p);
    pack_b0     <<<2,   256, 0, stream>>>(b_in, k0, bb0, b0p);
    pack_wout   <<<16,  256, 0, stream>>>(W_out, woutp);
    acclstm_main<<<256, 512, 0, stream>>>(x, wl1p, rk0p, w0p, woutp,
                                          b0p, bb1, b_out, out);
}